// Round 8
// baseline (107.751 us; speedup 1.0000x reference)
//
#include <hip/hip_runtime.h>
#include <math.h>

#define PI_D 3.14159265358979323846
#define PIF  3.14159265358979323846f
#define NLAT 128
#define NLON 256
#define LMAX 50
#define MMAX 50
#define NPTS 2048
#define NBT 16
#define NBA 32
#define NBIN (NBT * NBA)
#define WBIN 0.19634954084936207f   /* pi/16 */
#define INVW 5.092958178940651f     /* 16/pi */
#define BIG 1e30f
#define KMASK 0xFFFFF800u           /* high 21 bits of distance, low 11 = index */

__device__ __forceinline__ void insert3(float kf, float& k0, float& k1, float& k2) {
    float n1 = __builtin_amdgcn_fmed3f(kf, k0, k1);
    float n2 = __builtin_amdgcn_fmed3f(kf, k1, k2);
    k0 = fminf(kf, k0);
    k1 = n1;
    k2 = n2;
}

__device__ __forceinline__ float mkkey(float gt, float gl, float2 tl, int idx) {
    float dt = gt - tl.x, dl = gl - tl.y;
    float d = fmaf(dt, dt, dl * dl);
    return __uint_as_float((__float_as_uint(d) & KMASK) | (unsigned)idx);
}

// ---------------------------------------------------------------------------
// Kernel A: PCTW table, f32 (cost/sint via f64 sin/cos to dodge 1-cos^2
// cancellation; div/sqrt loops in f32 -- integer products < 2^24 are exact).
// One block per latitude node k; lane = m. Block 0 zeroes out[0].
// ---------------------------------------------------------------------------
__global__ __launch_bounds__(64) void pctw_kernel(float* __restrict__ pctwT,
                                                  float* __restrict__ out) {
    int k = blockIdx.x;      // 0..127
    int m = threadIdx.x;     // lane = m
    if (k == 0 && m == 0) out[0] = 0.0f;   // init for contract's atomics
    if (m >= MMAX) return;

    double thd = PI_D * (double)k / 127.0;
    float cost = (float)cos(thd);
    float sint = (float)sin(thd);          // >= 0 on [0,pi]

    // Clenshaw-Curtis weight (Nn=127, odd), f32 Chebyshev recurrence
    float c2 = (float)cos(2.0 * thd);
    float two_c2 = 2.0f * c2;
    float cp = 1.0f, cc = c2, v = 0.0f;
    for (int tt = 1; tt <= 63; ++tt) {
        v += 2.0f * cc / (float)(4 * tt * tt - 1);
        float cn = two_c2 * cc - cp;
        cp = cc;
        cc = cn;
    }
    float w = (2.0f / 127.0f) * (1.0f - v);
    if (k == 0 || k == 127) w *= 0.5f;

    float pmm = sqrtf(1.0f / (4.0f * PIF));
    for (int i = 1; i <= m; ++i)
        pmm = -pmm * sqrtf((2.0f * (float)i + 1.0f) / (2.0f * (float)i)) * sint;

    float* o = pctwT + (size_t)k * MMAX + m;   // pctwT[(l*NLAT+k)*MMAX+m]
    for (int l = 0; l < m; ++l) o[(size_t)l * NLAT * MMAX] = 0.0f;
    o[(size_t)m * NLAT * MMAX] = pmm * w;
    float plm2 = pmm, plm1 = 0.0f;
    if (m + 1 < LMAX) {
        plm1 = sqrtf(2.0f * (float)m + 3.0f) * cost * pmm;
        o[(size_t)(m + 1) * NLAT * MMAX] = plm1 * w;
    }
    for (int l = m + 2; l < LMAX; ++l) {
        float fl = (float)l;
        float denom = fl * fl - (float)(m * m);          // exact (<2^24)
        float a = sqrtf((4.0f * fl * fl - 1.0f) / denom);
        float b = sqrtf(((2.0f * fl + 1.0f) * (float)(l - 1 + m) * (float)(l - 1 - m)) /
                        ((2.0f * fl - 3.0f) * denom));
        float p = a * cost * plm1 - b * plm2;
        o[(size_t)l * NLAT * MMAX] = p * w;
        plm2 = plm1;
        plm1 = p;
    }
}

// ---------------------------------------------------------------------------
// Kernel B: binned 3-NN + interp + DFT. One block per (field, lat row).
// Wave-uniform scan: wave w's lanes span az-bins [8w,8w+7]; scan the uniform
// superset [8w-1, 8w+8] x [bt0-1, bt0+1] -- all LDS reads are broadcasts.
// ---------------------------------------------------------------------------
__global__ __launch_bounds__(256) void knn_kernel(const float* __restrict__ pred,
                                                  const float* __restrict__ tgt,
                                                  float* __restrict__ fre) {
    __shared__ float2 s_btl[NPTS];     // (theta, az) in bin order   16 KB
    __shared__ float  s_br[NPTS];      // radius in bin order         8 KB
    __shared__ int    s_cnt[NBIN];     // counts, then scatter cursor 2 KB
    __shared__ int    s_off[NBIN + 1]; // bin start offsets           2 KB
    __shared__ float  ctab[NLON];
    __shared__ float  row[NLON];
    __shared__ float  part[200];

    int bid = blockIdx.x;   // 0..511
    int t = threadIdx.x;
    int f = bid >> 7;
    int lat = bid & 127;
    const float* src = ((f < 2) ? pred : tgt) + (size_t)(f & 1) * NPTS * 3;

    s_cnt[t] = 0;
    s_cnt[t + 256] = 0;
    ctab[t] = (float)cos(2.0 * PI_D * (double)t / (double)NLON);
    __syncthreads();

    // to_spherical into registers (exact reference fp order) + bin counts
    float pth[8], paz[8], pr[8];
    int pbin[8];
#pragma unroll
    for (int i = 0; i < 8; ++i) {
        int n = t + 256 * i;
        float x = src[3 * n], y = src[3 * n + 1], z = src[3 * n + 2];
        float s1 = z * z;
        float s2 = s1 + y * y;
        float s3 = s2 + x * x;
        float r = sqrtf(s3);
        float rho = sqrtf(s2);
        float th = acosf(x / r);
        float a = acosf(y / rho);
        float az = (z < 0.0f) ? (a + (2.0f * PIF - 2.0f * a)) : a;
        az -= PIF;
        int bt = min(max((int)(th * INVW), 0), NBT - 1);
        int ba = min(max((int)((az + PIF) * INVW), 0), NBA - 1);
        int b = bt * NBA + ba;
        pth[i] = th; paz[i] = az; pr[i] = r; pbin[i] = b;
        atomicAdd(&s_cnt[b], 1);
    }
    __syncthreads();

    // exclusive scan of 512 counts by one wave (8 bins per lane)
    if (t == 0) s_off[NBIN] = NPTS;
    if (t < 64) {
        int base = t * 8;
        int loc[8];
        int run = 0;
#pragma unroll
        for (int i = 0; i < 8; ++i) { loc[i] = run; run += s_cnt[base + i]; }
        int x = run;
#pragma unroll
        for (int d = 1; d < 64; d <<= 1) {
            int y = __shfl_up(x, d);
            if (t >= d) x += y;
        }
        int ex = x - run;
#pragma unroll
        for (int i = 0; i < 8; ++i) s_off[base + i] = ex + loc[i];
    }
    __syncthreads();
    s_cnt[t] = s_off[t];
    s_cnt[t + 256] = s_off[t + 256];
    __syncthreads();
#pragma unroll
    for (int i = 0; i < 8; ++i) {
        int pos = atomicAdd(&s_cnt[pbin[i]], 1);
        s_btl[pos] = make_float2(pth[i], paz[i]);
        s_br[pos] = pr[i];
    }
    __syncthreads();

    // ---- wave-uniform 3-NN query ----
    int j = t;
    int wv = t >> 6;    // wave id: lanes span az-bins [8wv, 8wv+7]
    float gt = (float)((double)lat * PI_D / 128.0);
    float gl = (float)(((double)j - 128.0) * PI_D / 128.0);
    float glp = gl + PIF;
    int bt0 = lat >> 3;                     // block-uniform
    int lo_a = max(wv * 8 - 1, 0);          // wave-uniform az range
    int hi_a = min(wv * 8 + 8, NBA - 1);
    int rlo = max(bt0 - 1, 0), rhi = min(bt0 + 1, NBT - 1);

    float k0 = BIG, k1 = BIG, k2 = BIG;
    for (int bt = rlo; bt <= rhi; ++bt) {
        int i = s_off[bt * NBA + lo_a];     // uniform -> broadcast reads
        int i1 = s_off[bt * NBA + hi_a + 1];
#pragma unroll 4
        for (; i < i1; ++i)
            insert3(mkkey(gt, gl, s_btl[i], i), k0, k1, k2);
    }

    // per-lane safe-radius vs the wave-scanned rectangle
    bool done;
    {
        float safe = BIG;
        if (bt0 - 1 > 0)       safe = fminf(safe, gt - (float)(bt0 - 1) * WBIN);
        if (bt0 + 1 < NBT - 1) safe = fminf(safe, (float)(bt0 + 2) * WBIN - gt);
        if (lo_a > 0)          safe = fminf(safe, glp - (float)lo_a * WBIN);
        if (hi_a < NBA - 1)    safe = fminf(safe, (float)(hi_a + 1) * WBIN - glp);
        done = (k2 <= safe * safe);
    }

    // fallback: fresh triple, full theta-rows outward (uniform, broadcast;
    // full rows cover the whole az domain so only theta bounds the safety)
    if (__any(!done)) {
        float q0 = BIG, q1 = BIG, q2 = BIG;
        int lo = rlo, hi = rhi;
        for (int bt = rlo; bt <= rhi; ++bt) {
            int i = s_off[bt * NBA], i1 = s_off[(bt + 1) * NBA];
#pragma unroll 4
            for (; i < i1; ++i)
                insert3(mkkey(gt, gl, s_btl[i], i), q0, q1, q2);
        }
        while (true) {
            float sf = BIG;
            if (lo > 0)       sf = fminf(sf, gt - (float)lo * WBIN);
            if (hi < NBT - 1) sf = fminf(sf, (float)(hi + 1) * WBIN - gt);
            if (__all(q2 <= sf * sf) || (lo == 0 && hi == NBT - 1)) break;
            if (lo > 0) {
                --lo;
                int i = s_off[lo * NBA], i1 = s_off[(lo + 1) * NBA];
#pragma unroll 4
                for (; i < i1; ++i)
                    insert3(mkkey(gt, gl, s_btl[i], i), q0, q1, q2);
            }
            if (hi < NBT - 1) {
                ++hi;
                int i = s_off[hi * NBA], i1 = s_off[(hi + 1) * NBA];
#pragma unroll 4
                for (; i < i1; ++i)
                    insert3(mkkey(gt, gl, s_btl[i], i), q0, q1, q2);
            }
        }
        if (!done) { k0 = q0; k1 = q1; k2 = q2; }
    }

    // epilogue: indices from keys, exact distances, interp weights
    {
        int i0 = __float_as_uint(k0) & 0x7FF;
        int i1 = __float_as_uint(k1) & 0x7FF;
        int i2 = __float_as_uint(k2) & 0x7FF;
        float2 p0 = s_btl[i0];
        float2 p1 = s_btl[i1];
        float2 p2 = s_btl[i2];
        float dt0 = gt - p0.x, dl0 = gl - p0.y;
        float dt1 = gt - p1.x, dl1 = gl - p1.y;
        float dt2 = gt - p2.x, dl2 = gl - p2.y;
        float d0 = fmaf(dt0, dt0, dl0 * dl0);
        float d1 = fmaf(dt1, dt1, dl1 * dl1);
        float d2 = fmaf(dt2, dt2, dl2 * dl2);
        float s = d0 + d1 + d2;
        row[j] = (d0 * s_br[i0] + d1 * s_br[i1] + d2 * s_br[i2]) / s;
    }
    __syncthreads();

    // DFT of the row: 50 modes x 4 partial sums of 64 (threads 0..199)
    if (t < 200) {
        int mm = t >> 2, q = t & 3;
        int bs = q * 64;
        float acc = 0.0f;
        int p = (bs * mm) & (NLON - 1);
        for (int i = 0; i < 64; ++i) {
            acc += row[bs + i] * ctab[p];
            p = (p + mm) & (NLON - 1);
        }
        part[t] = acc;
    }
    __syncthreads();
    if (t < MMAX) {
        const float* pp = part + t * 4;
        fre[(f * NLAT + lat) * MMAX + t] =
            ((pp[0] + pp[1]) + (pp[2] + pp[3])) * (float)(2.0 * PI_D / (double)NLON);
    }
}

// ---------------------------------------------------------------------------
// Kernel C: Legendre contraction + loss. Block per (b,l); 256 threads =
// (mm 0..63) x (k-quarter 0..3); LDS reduce; one atomic per block.
// ---------------------------------------------------------------------------
__global__ __launch_bounds__(256) void contract_loss(const float* __restrict__ fre,
                                                     const float* __restrict__ pctwT,
                                                     float* __restrict__ out) {
    int b = blockIdx.x / LMAX;
    int l = blockIdx.x % LMAX;
    int mm = threadIdx.x & 63;
    int kq = threadIdx.x >> 6;
    __shared__ float sp[4][64], st_[4][64];
    float pc = 0.0f, tc = 0.0f;
    if (mm < MMAX) {
        const float* pw = pctwT + ((size_t)l * NLAT + kq * 32) * MMAX + mm;
        const float* fp = fre + ((size_t)b * NLAT + kq * 32) * MMAX + mm;
        const float* ft = fre + ((size_t)(2 + b) * NLAT + kq * 32) * MMAX + mm;
#pragma unroll 8
        for (int k = 0; k < 32; ++k) {
            float w = pw[k * MMAX];
            pc += fp[k * MMAX] * w;
            tc += ft[k * MMAX] * w;
        }
    }
    sp[kq][mm] = pc;
    st_[kq][mm] = tc;
    __syncthreads();
    if (threadIdx.x < 64) {
        int m2 = threadIdx.x;
        float pcs = (sp[0][m2] + sp[1][m2]) + (sp[2][m2] + sp[3][m2]);
        float tcs = (st_[0][m2] + st_[1][m2]) + (st_[2][m2] + st_[3][m2]);
        float diff = pcs - tcs;
        double dl_ = (double)(49 - l);
        float rw = (float)exp(-(dl_ * dl_) / 5000.0);
        float contrib = (m2 < MMAX) ? diff * diff * rw * 0.5f : 0.0f;
        for (int off = 32; off > 0; off >>= 1) contrib += __shfl_down(contrib, off);
        if (m2 == 0) atomicAdd(out, contrib);
    }
}

// ---------------------------------------------------------------------------
extern "C" void kernel_launch(void* const* d_in, const int* in_sizes, int n_in,
                              void* d_out, int out_size, void* d_ws, size_t ws_size,
                              hipStream_t stream) {
    const float* pred = (const float*)d_in[0];
    const float* tgt = (const float*)d_in[1];
    float* ws = (float*)d_ws;

    float* pctwT = ws;            // 50*128*50 = 320000 floats
    float* fre   = ws + 320000;   // 4*128*50  =  25600 floats
    float* out = (float*)d_out;

    knn_kernel<<<512, 256, 0, stream>>>(pred, tgt, fre);
    pctw_kernel<<<NLAT, 64, 0, stream>>>(pctwT, out);
    contract_loss<<<2 * LMAX, 256, 0, stream>>>(fre, pctwT, out);
}

// Round 9
// 91.295 us; speedup vs baseline: 1.1803x; 1.1803x over previous
//
#include <hip/hip_runtime.h>
#include <math.h>

#define PI_D 3.14159265358979323846
#define PIF  3.14159265358979323846f
#define NLAT 128
#define NLON 256
#define LMAX 50
#define MMAX 50
#define NPTS 2048
#define NBT 16
#define NBA 32
#define NBIN (NBT * NBA)
#define WBIN 0.19634954084936207f   /* pi/16 */
#define INVW 5.092958178940651f     /* 16/pi */
#define BIG 1e30f
#define KMASK 0xFFFFF800u           /* high 21 bits of distance, low 11 = index */

__device__ __forceinline__ void insert3(float kf, float& k0, float& k1, float& k2) {
    float n1 = __builtin_amdgcn_fmed3f(kf, k0, k1);
    float n2 = __builtin_amdgcn_fmed3f(kf, k1, k2);
    k0 = fminf(kf, k0);
    k1 = n1;
    k2 = n2;
}

__device__ __forceinline__ float mkkey(float gt, float gl, float2 tl, int idx) {
    float dt = gt - tl.x, dl = gl - tl.y;
    float d = fmaf(dt, dt, dl * dl);
    return __uint_as_float((__float_as_uint(d) & KMASK) | (unsigned)idx);
}

// ---------------------------------------------------------------------------
// Kernel 1 (prep): blocks 0..3   = bin one field each, publish to global
//                  blocks 4..131 = PCTW column k = bid-4, f32 (lane = m)
//                  block 4 zeroes out[0] for the contract kernel's atomics.
// ---------------------------------------------------------------------------
__global__ __launch_bounds__(256) void prep_kernel(
    const float* __restrict__ pred, const float* __restrict__ tgt,
    float2* __restrict__ gbtl, float* __restrict__ gbr, int* __restrict__ goff,
    float* __restrict__ pctwT, float* __restrict__ out) {

    __shared__ float2 s_btl[NPTS];
    __shared__ float  s_br[NPTS];
    __shared__ int    s_cnt[NBIN];
    __shared__ int    s_off[NBIN + 1];

    int bid = blockIdx.x;
    int t = threadIdx.x;

    if (bid >= 4) {
        // ---------------- PCTW role, f32 ----------------
        int k = bid - 4;                        // 0..127
        int m = t;
        if (k == 0 && m == 0) out[0] = 0.0f;    // init for contract's atomics
        if (m >= MMAX) return;

        double thd = PI_D * (double)k / 127.0;
        float cost = (float)cos(thd);
        float sint = (float)sin(thd);           // >= 0 on [0,pi]

        // Clenshaw-Curtis weight (Nn=127, odd), f32 Chebyshev recurrence
        float c2 = (float)cos(2.0 * thd);
        float two_c2 = 2.0f * c2;
        float cp = 1.0f, cc = c2, v = 0.0f;
        for (int tt = 1; tt <= 63; ++tt) {
            v += 2.0f * cc / (float)(4 * tt * tt - 1);
            float cn = two_c2 * cc - cp;
            cp = cc;
            cc = cn;
        }
        float w = (2.0f / 127.0f) * (1.0f - v);
        if (k == 0 || k == 127) w *= 0.5f;

        float pmm = sqrtf(1.0f / (4.0f * PIF));
        for (int i = 1; i <= m; ++i)
            pmm = -pmm * sqrtf((2.0f * (float)i + 1.0f) / (2.0f * (float)i)) * sint;

        float* o = pctwT + (size_t)k * MMAX + m;   // pctwT[(l*NLAT+k)*MMAX+m]
        for (int l = 0; l < m; ++l) o[(size_t)l * NLAT * MMAX] = 0.0f;
        o[(size_t)m * NLAT * MMAX] = pmm * w;
        float plm2 = pmm, plm1 = 0.0f;
        if (m + 1 < LMAX) {
            plm1 = sqrtf(2.0f * (float)m + 3.0f) * cost * pmm;
            o[(size_t)(m + 1) * NLAT * MMAX] = plm1 * w;
        }
        for (int l = m + 2; l < LMAX; ++l) {
            float fl = (float)l;
            float denom = fl * fl - (float)(m * m);          // exact (<2^24)
            float a = sqrtf((4.0f * fl * fl - 1.0f) / denom);
            float b = sqrtf(((2.0f * fl + 1.0f) * (float)(l - 1 + m) * (float)(l - 1 - m)) /
                            ((2.0f * fl - 3.0f) * denom));
            float p = a * cost * plm1 - b * plm2;
            o[(size_t)l * NLAT * MMAX] = p * w;
            plm2 = plm1;
            plm1 = p;
        }
        return;
    }

    // ---------------- bin role: one field per block ----------------
    int f = bid;
    const float* src = ((f < 2) ? pred : tgt) + (size_t)(f & 1) * NPTS * 3;

    s_cnt[t] = 0;
    s_cnt[t + 256] = 0;
    __syncthreads();

    // to_spherical into registers (exact reference fp order) + bin counts
    float pth[8], paz[8], pr[8];
    int pbin[8];
#pragma unroll
    for (int i = 0; i < 8; ++i) {
        int n = t + 256 * i;
        float x = src[3 * n], y = src[3 * n + 1], z = src[3 * n + 2];
        float s1 = z * z;
        float s2 = s1 + y * y;
        float s3 = s2 + x * x;
        float r = sqrtf(s3);
        float rho = sqrtf(s2);
        float th = acosf(x / r);
        float a = acosf(y / rho);
        float az = (z < 0.0f) ? (a + (2.0f * PIF - 2.0f * a)) : a;
        az -= PIF;
        int bt = min(max((int)(th * INVW), 0), NBT - 1);
        int ba = min(max((int)((az + PIF) * INVW), 0), NBA - 1);
        int b = bt * NBA + ba;
        pth[i] = th; paz[i] = az; pr[i] = r; pbin[i] = b;
        atomicAdd(&s_cnt[b], 1);
    }
    __syncthreads();

    // exclusive scan of 512 counts by one wave (8 bins per lane)
    if (t == 0) s_off[NBIN] = NPTS;
    if (t < 64) {
        int base = t * 8;
        int loc[8];
        int run = 0;
#pragma unroll
        for (int i = 0; i < 8; ++i) { loc[i] = run; run += s_cnt[base + i]; }
        int x = run;
#pragma unroll
        for (int d = 1; d < 64; d <<= 1) {
            int y = __shfl_up(x, d);
            if (t >= d) x += y;
        }
        int ex = x - run;
#pragma unroll
        for (int i = 0; i < 8; ++i) s_off[base + i] = ex + loc[i];
    }
    __syncthreads();
    s_cnt[t] = s_off[t];
    s_cnt[t + 256] = s_off[t + 256];
    __syncthreads();
#pragma unroll
    for (int i = 0; i < 8; ++i) {
        int pos = atomicAdd(&s_cnt[pbin[i]], 1);
        s_btl[pos] = make_float2(pth[i], paz[i]);
        s_br[pos] = pr[i];
    }
    __syncthreads();

    // publish binned arrays (coalesced)
    for (int n = t; n < NPTS; n += 256) {
        gbtl[(size_t)f * NPTS + n] = s_btl[n];
        gbr[(size_t)f * NPTS + n] = s_br[n];
    }
    for (int n = t; n <= NBIN; n += 256) goff[f * (NBIN + 1) + n] = s_off[n];
}

// ---------------------------------------------------------------------------
// Kernel 2 (knn): one block per (field, lat row). Prologue = coalesced LDS
// stage of pre-binned data (one __syncthreads). Scan/fallback = R6 verbatim.
// ---------------------------------------------------------------------------
__global__ __launch_bounds__(256) void knn_kernel(
    const float2* __restrict__ gbtl, const float* __restrict__ gbr,
    const int* __restrict__ goff, float* __restrict__ fre) {

    __shared__ float2 s_btl[NPTS];     // 16 KB
    __shared__ float  s_br[NPTS];      //  8 KB
    __shared__ int    s_off[NBIN + 1]; //  2 KB
    __shared__ float  ctab[NLON];
    __shared__ float  row[NLON];
    __shared__ float  part[200];

    int bid = blockIdx.x;   // 0..511
    int t = threadIdx.x;
    int f = bid >> 7;
    int lat = bid & 127;

    // stage binned data: float4 coalesced
    {
        const float4* b4 = (const float4*)(gbtl + (size_t)f * NPTS);
        float4* s4 = (float4*)s_btl;
        for (int i = t; i < NPTS / 2; i += 256) s4[i] = b4[i];
        const float4* r4 = (const float4*)(gbr + (size_t)f * NPTS);
        float4* sr4 = (float4*)s_br;
        for (int i = t; i < NPTS / 4; i += 256) sr4[i] = r4[i];
        const int* go = goff + f * (NBIN + 1);
        for (int i = t; i <= NBIN; i += 256) s_off[i] = go[i];
        ctab[t] = (float)cos(2.0 * PI_D * (double)t / (double)NLON);
    }
    __syncthreads();

    // ---- 3-NN query: one grid point per thread, packed keys (R6) ----
    int j = t;
    float gt = (float)((double)lat * PI_D / 128.0);
    float gl = (float)(((double)j - 128.0) * PI_D / 128.0);
    float glp = gl + PIF;
    int bt0 = lat >> 3;
    int ba0 = j >> 3;

    auto scan_seg = [&](int i, int i1, float& q0, float& q1, float& q2) {
        for (; i + 4 <= i1; i += 4) {
            float2 a0 = s_btl[i];
            float2 a1 = s_btl[i + 1];
            float2 a2 = s_btl[i + 2];
            float2 a3 = s_btl[i + 3];
            insert3(mkkey(gt, gl, a0, i), q0, q1, q2);
            insert3(mkkey(gt, gl, a1, i + 1), q0, q1, q2);
            insert3(mkkey(gt, gl, a2, i + 2), q0, q1, q2);
            insert3(mkkey(gt, gl, a3, i + 3), q0, q1, q2);
        }
        for (; i < i1; ++i)
            insert3(mkkey(gt, gl, s_btl[i], i), q0, q1, q2);
    };

    float k0 = BIG, k1 = BIG, k2 = BIG;
    {
        int rtl = max(bt0 - 1, 0), rth = min(bt0 + 1, NBT - 1);
        int bal = max(ba0 - 1, 0), bah = min(ba0 + 1, NBA - 1);
        for (int bt = rtl; bt <= rth; ++bt)
            scan_seg(s_off[bt * NBA + bal], s_off[bt * NBA + bah + 1], k0, k1, k2);
    }

    bool done;
    {
        float safe = BIG;
        if (bt0 - 1 > 0)       safe = fminf(safe, gt - (float)(bt0 - 1) * WBIN);
        if (bt0 + 1 < NBT - 1) safe = fminf(safe, (float)(bt0 + 2) * WBIN - gt);
        if (ba0 - 1 > 0)       safe = fminf(safe, glp - (float)(ba0 - 1) * WBIN);
        if (ba0 + 1 < NBA - 1) safe = fminf(safe, (float)(ba0 + 2) * WBIN - glp);
        done = (k2 <= safe * safe);
    }

    // fallback: expanding rings R>=2 (R6 verbatim)
    for (int R = 2; R <= 31; ++R) {
        if (__all(done)) break;
        if (!done) {
            int btl = bt0 - R, bth = bt0 + R;
            int lo = max(btl, 0), hi = min(bth, NBT - 1);
            int bal = max(ba0 - R, 0), bah = min(ba0 + R, NBA - 1);
            for (int bt = lo; bt <= hi; ++bt) {
                if (bt == btl || bt == bth) {
                    scan_seg(s_off[bt * NBA + bal], s_off[bt * NBA + bah + 1], k0, k1, k2);
                } else {
                    if (ba0 - R >= 0) {
                        int b = bt * NBA + ba0 - R;
                        scan_seg(s_off[b], s_off[b + 1], k0, k1, k2);
                    }
                    if (ba0 + R <= NBA - 1) {
                        int b = bt * NBA + ba0 + R;
                        scan_seg(s_off[b], s_off[b + 1], k0, k1, k2);
                    }
                }
            }
            float safe = BIG;
            if (bt0 - R > 0)       safe = fminf(safe, gt - (float)(bt0 - R) * WBIN);
            if (bt0 + R < NBT - 1) safe = fminf(safe, (float)(bt0 + R + 1) * WBIN - gt);
            if (ba0 - R > 0)       safe = fminf(safe, glp - (float)(ba0 - R) * WBIN);
            if (ba0 + R < NBA - 1) safe = fminf(safe, (float)(ba0 + R + 1) * WBIN - glp);
            if (k2 <= safe * safe) done = true;
        }
    }

    // epilogue: indices from keys, exact distances, interp weights
    {
        int i0 = __float_as_uint(k0) & 0x7FF;
        int i1 = __float_as_uint(k1) & 0x7FF;
        int i2 = __float_as_uint(k2) & 0x7FF;
        float2 p0 = s_btl[i0];
        float2 p1 = s_btl[i1];
        float2 p2 = s_btl[i2];
        float dt0 = gt - p0.x, dl0 = gl - p0.y;
        float dt1 = gt - p1.x, dl1 = gl - p1.y;
        float dt2 = gt - p2.x, dl2 = gl - p2.y;
        float d0 = fmaf(dt0, dt0, dl0 * dl0);
        float d1 = fmaf(dt1, dt1, dl1 * dl1);
        float d2 = fmaf(dt2, dt2, dl2 * dl2);
        float s = d0 + d1 + d2;
        row[j] = (d0 * s_br[i0] + d1 * s_br[i1] + d2 * s_br[i2]) / s;
    }
    __syncthreads();

    // DFT of the row: 50 modes x 4 partial sums of 64 (threads 0..199),
    // unrolled x4 with independent twiddle indices (8 LDS reads in flight)
    if (t < 200) {
        int mm = t >> 2, q = t & 3;
        int bs = q * 64;
        float a0 = 0.0f, a1 = 0.0f, a2 = 0.0f, a3 = 0.0f;
        int p = (bs * mm) & (NLON - 1);
        int st1 = mm & (NLON - 1);
        int st2 = (2 * mm) & (NLON - 1);
        int st3 = (3 * mm) & (NLON - 1);
        int st4 = (4 * mm) & (NLON - 1);
        for (int i = 0; i < 64; i += 4) {
            a0 += row[bs + i] * ctab[p];
            a1 += row[bs + i + 1] * ctab[(p + st1) & (NLON - 1)];
            a2 += row[bs + i + 2] * ctab[(p + st2) & (NLON - 1)];
            a3 += row[bs + i + 3] * ctab[(p + st3) & (NLON - 1)];
            p = (p + st4) & (NLON - 1);
        }
        part[t] = (a0 + a1) + (a2 + a3);
    }
    __syncthreads();
    if (t < MMAX) {
        const float* pp = part + t * 4;
        fre[(f * NLAT + lat) * MMAX + t] =
            ((pp[0] + pp[1]) + (pp[2] + pp[3])) * (float)(2.0 * PI_D / (double)NLON);
    }
}

// ---------------------------------------------------------------------------
// Kernel 3: Legendre contraction + loss (R6 verbatim). Block per (b,l).
// ---------------------------------------------------------------------------
__global__ __launch_bounds__(256) void contract_loss(const float* __restrict__ fre,
                                                     const float* __restrict__ pctwT,
                                                     float* __restrict__ out) {
    int b = blockIdx.x / LMAX;
    int l = blockIdx.x % LMAX;
    int mm = threadIdx.x & 63;
    int kq = threadIdx.x >> 6;
    __shared__ float sp[4][64], st_[4][64];
    float pc = 0.0f, tc = 0.0f;
    if (mm < MMAX) {
        const float* pw = pctwT + ((size_t)l * NLAT + kq * 32) * MMAX + mm;
        const float* fp = fre + ((size_t)b * NLAT + kq * 32) * MMAX + mm;
        const float* ft = fre + ((size_t)(2 + b) * NLAT + kq * 32) * MMAX + mm;
#pragma unroll 8
        for (int k = 0; k < 32; ++k) {
            float w = pw[k * MMAX];
            pc += fp[k * MMAX] * w;
            tc += ft[k * MMAX] * w;
        }
    }
    sp[kq][mm] = pc;
    st_[kq][mm] = tc;
    __syncthreads();
    if (threadIdx.x < 64) {
        int m2 = threadIdx.x;
        float pcs = (sp[0][m2] + sp[1][m2]) + (sp[2][m2] + sp[3][m2]);
        float tcs = (st_[0][m2] + st_[1][m2]) + (st_[2][m2] + st_[3][m2]);
        float diff = pcs - tcs;
        double dl_ = (double)(49 - l);
        float rw = (float)exp(-(dl_ * dl_) / 5000.0);
        float contrib = (m2 < MMAX) ? diff * diff * rw * 0.5f : 0.0f;
        for (int off = 32; off > 0; off >>= 1) contrib += __shfl_down(contrib, off);
        if (m2 == 0) atomicAdd(out, contrib);
    }
}

// ---------------------------------------------------------------------------
extern "C" void kernel_launch(void* const* d_in, const int* in_sizes, int n_in,
                              void* d_out, int out_size, void* d_ws, size_t ws_size,
                              hipStream_t stream) {
    const float* pred = (const float*)d_in[0];
    const float* tgt = (const float*)d_in[1];
    float* ws = (float*)d_ws;

    // ws layout (floats):
    float*  pctwT = ws;                          // 50*128*50 = 320000
    float*  fre   = ws + 320000;                 // 4*128*50  =  25600
    float2* gbtl  = (float2*)(ws + 345600);      // 4*2048 float2 = 16384 floats
    float*  gbr   = ws + 345600 + 16384;         // 4*2048 =  8192
    int*    goff  = (int*)(ws + 345600 + 16384 + 8192);  // 4*513 ints
    float* out = (float*)d_out;

    prep_kernel<<<132, 256, 0, stream>>>(pred, tgt, gbtl, gbr, goff, pctwT, out);
    knn_kernel<<<512, 256, 0, stream>>>(gbtl, gbr, goff, fre);
    contract_loss<<<2 * LMAX, 256, 0, stream>>>(fre, pctwT, out);
}

// Round 10
// 84.114 us; speedup vs baseline: 1.2810x; 1.0854x over previous
//
#include <hip/hip_runtime.h>
#include <math.h>

#define PI_D 3.14159265358979323846
#define PIF  3.14159265358979323846f
#define NLAT 128
#define NLON 256
#define LMAX 50
#define MMAX 50
#define NPTS 2048
#define NBT 16
#define NBA 32
#define NBIN (NBT * NBA)
#define WBIN 0.19634954084936207f   /* pi/16 */
#define INVW 5.092958178940651f     /* 16/pi */
#define BIG 1e30f
#define KMASK 0xFFFFF800u           /* high 21 bits of distance, low 11 = index */

__device__ __forceinline__ void insert3(float kf, float& k0, float& k1, float& k2) {
    float n1 = __builtin_amdgcn_fmed3f(kf, k0, k1);
    float n2 = __builtin_amdgcn_fmed3f(kf, k1, k2);
    k0 = fminf(kf, k0);
    k1 = n1;
    k2 = n2;
}

__device__ __forceinline__ float mkkey(float gt, float gl, float2 tl, int idx) {
    float dt = gt - tl.x, dl = gl - tl.y;
    float d = fmaf(dt, dt, dl * dl);
    return __uint_as_float((__float_as_uint(d) & KMASK) | (unsigned)idx);
}

// ---------------------------------------------------------------------------
// Kernel 1 (fused): blocks 0..511  = binned knn + interp + DFT (one field,lat)
//                   blocks 512..639 = PCTW column k = bid-512, f32 (lane = m).
//                   Block 512 zeroes out[0] for kernel 2's atomics.
// ---------------------------------------------------------------------------
__global__ __launch_bounds__(256) void fused_main(
    const float* __restrict__ pred, const float* __restrict__ tgt,
    float* __restrict__ pctwT, float* __restrict__ fre, float* __restrict__ out) {

    __shared__ float2 s_btl[NPTS];     // (theta, az) in bin order   16 KB
    __shared__ float  s_br[NPTS];      // radius in bin order         8 KB
    __shared__ int    s_cnt[NBIN];     // counts, then scatter cursor 2 KB
    __shared__ int    s_off[NBIN + 1]; // bin start offsets           2 KB
    __shared__ float  ctab[NLON];
    __shared__ float  row[NLON];
    __shared__ float  part[256];

    int bid = blockIdx.x;
    int t = threadIdx.x;

    if (bid >= 512) {
        // ---------------- PCTW role, f32 (R9-validated) ----------------
        int k = bid - 512;                      // 0..127
        int m = t;
        if (k == 0 && m == 0) out[0] = 0.0f;    // init for contract's atomics
        if (m >= MMAX) return;

        double thd = PI_D * (double)k / 127.0;
        float cost = (float)cos(thd);
        float sint = (float)sin(thd);           // >= 0 on [0,pi]

        // Clenshaw-Curtis weight (Nn=127, odd), f32 Chebyshev recurrence
        float c2 = (float)cos(2.0 * thd);
        float two_c2 = 2.0f * c2;
        float cp = 1.0f, cc = c2, v = 0.0f;
        for (int tt = 1; tt <= 63; ++tt) {
            v += 2.0f * cc / (float)(4 * tt * tt - 1);
            float cn = two_c2 * cc - cp;
            cp = cc;
            cc = cn;
        }
        float w = (2.0f / 127.0f) * (1.0f - v);
        if (k == 0 || k == 127) w *= 0.5f;

        float pmm = sqrtf(1.0f / (4.0f * PIF));
        for (int i = 1; i <= m; ++i)
            pmm = -pmm * sqrtf((2.0f * (float)i + 1.0f) / (2.0f * (float)i)) * sint;

        float* o = pctwT + (size_t)k * MMAX + m;   // pctwT[(l*NLAT+k)*MMAX+m]
        for (int l = 0; l < m; ++l) o[(size_t)l * NLAT * MMAX] = 0.0f;
        o[(size_t)m * NLAT * MMAX] = pmm * w;
        float plm2 = pmm, plm1 = 0.0f;
        if (m + 1 < LMAX) {
            plm1 = sqrtf(2.0f * (float)m + 3.0f) * cost * pmm;
            o[(size_t)(m + 1) * NLAT * MMAX] = plm1 * w;
        }
        for (int l = m + 2; l < LMAX; ++l) {
            float fl = (float)l;
            float denom = fl * fl - (float)(m * m);          // exact (<2^24)
            float a = sqrtf((4.0f * fl * fl - 1.0f) / denom);
            float b = sqrtf(((2.0f * fl + 1.0f) * (float)(l - 1 + m) * (float)(l - 1 - m)) /
                            ((2.0f * fl - 3.0f) * denom));
            float p = a * cost * plm1 - b * plm2;
            o[(size_t)l * NLAT * MMAX] = p * w;
            plm2 = plm1;
            plm1 = p;
        }
        return;
    }

    // ---------------- KNN role (R6 verbatim) ----------------
    int f = bid >> 7;
    int lat = bid & 127;
    const float* src = ((f < 2) ? pred : tgt) + (size_t)(f & 1) * NPTS * 3;

    s_cnt[t] = 0;
    s_cnt[t + 256] = 0;
    ctab[t] = (float)cos(2.0 * PI_D * (double)t / (double)NLON);
    __syncthreads();

    // to_spherical into registers (exact reference fp order) + bin counts
    float pth[8], paz[8], pr[8];
    int pbin[8];
#pragma unroll
    for (int i = 0; i < 8; ++i) {
        int n = t + 256 * i;
        float x = src[3 * n], y = src[3 * n + 1], z = src[3 * n + 2];
        float s1 = z * z;
        float s2 = s1 + y * y;
        float s3 = s2 + x * x;
        float r = sqrtf(s3);
        float rho = sqrtf(s2);
        float th = acosf(x / r);
        float a = acosf(y / rho);
        float az = (z < 0.0f) ? (a + (2.0f * PIF - 2.0f * a)) : a;
        az -= PIF;
        int bt = min(max((int)(th * INVW), 0), NBT - 1);
        int ba = min(max((int)((az + PIF) * INVW), 0), NBA - 1);
        int b = bt * NBA + ba;
        pth[i] = th; paz[i] = az; pr[i] = r; pbin[i] = b;
        atomicAdd(&s_cnt[b], 1);
    }
    __syncthreads();

    // exclusive scan of 512 counts by one wave (8 bins per lane)
    if (t == 0) s_off[NBIN] = NPTS;
    if (t < 64) {
        int base = t * 8;
        int loc[8];
        int run = 0;
#pragma unroll
        for (int i = 0; i < 8; ++i) { loc[i] = run; run += s_cnt[base + i]; }
        int x = run;
#pragma unroll
        for (int d = 1; d < 64; d <<= 1) {
            int y = __shfl_up(x, d);
            if (t >= d) x += y;
        }
        int ex = x - run;
#pragma unroll
        for (int i = 0; i < 8; ++i) s_off[base + i] = ex + loc[i];
    }
    __syncthreads();
    s_cnt[t] = s_off[t];
    s_cnt[t + 256] = s_off[t + 256];
    __syncthreads();
#pragma unroll
    for (int i = 0; i < 8; ++i) {
        int pos = atomicAdd(&s_cnt[pbin[i]], 1);
        s_btl[pos] = make_float2(pth[i], paz[i]);
        s_br[pos] = pr[i];
    }
    __syncthreads();

    // ---- 3-NN query: one grid point per thread, packed keys ----
    int j = t;
    float gt = (float)((double)lat * PI_D / 128.0);
    float gl = (float)(((double)j - 128.0) * PI_D / 128.0);
    float glp = gl + PIF;
    int bt0 = lat >> 3;
    int ba0 = j >> 3;

    auto scan_seg = [&](int i, int i1, float& q0, float& q1, float& q2) {
        for (; i + 4 <= i1; i += 4) {
            float2 a0 = s_btl[i];
            float2 a1 = s_btl[i + 1];
            float2 a2 = s_btl[i + 2];
            float2 a3 = s_btl[i + 3];
            insert3(mkkey(gt, gl, a0, i), q0, q1, q2);
            insert3(mkkey(gt, gl, a1, i + 1), q0, q1, q2);
            insert3(mkkey(gt, gl, a2, i + 2), q0, q1, q2);
            insert3(mkkey(gt, gl, a3, i + 3), q0, q1, q2);
        }
        for (; i < i1; ++i)
            insert3(mkkey(gt, gl, s_btl[i], i), q0, q1, q2);
    };

    float k0 = BIG, k1 = BIG, k2 = BIG;
    {
        int rtl = max(bt0 - 1, 0), rth = min(bt0 + 1, NBT - 1);
        int bal = max(ba0 - 1, 0), bah = min(ba0 + 1, NBA - 1);
        for (int bt = rtl; bt <= rth; ++bt)
            scan_seg(s_off[bt * NBA + bal], s_off[bt * NBA + bah + 1], k0, k1, k2);
    }

    bool done;
    {
        float safe = BIG;
        if (bt0 - 1 > 0)       safe = fminf(safe, gt - (float)(bt0 - 1) * WBIN);
        if (bt0 + 1 < NBT - 1) safe = fminf(safe, (float)(bt0 + 2) * WBIN - gt);
        if (ba0 - 1 > 0)       safe = fminf(safe, glp - (float)(ba0 - 1) * WBIN);
        if (ba0 + 1 < NBA - 1) safe = fminf(safe, (float)(ba0 + 2) * WBIN - glp);
        done = (k2 <= safe * safe);
    }

    // fallback: expanding rings R>=2 (R6 verbatim)
    for (int R = 2; R <= 31; ++R) {
        if (__all(done)) break;
        if (!done) {
            int btl = bt0 - R, bth = bt0 + R;
            int lo = max(btl, 0), hi = min(bth, NBT - 1);
            int bal = max(ba0 - R, 0), bah = min(ba0 + R, NBA - 1);
            for (int bt = lo; bt <= hi; ++bt) {
                if (bt == btl || bt == bth) {
                    scan_seg(s_off[bt * NBA + bal], s_off[bt * NBA + bah + 1], k0, k1, k2);
                } else {
                    if (ba0 - R >= 0) {
                        int b = bt * NBA + ba0 - R;
                        scan_seg(s_off[b], s_off[b + 1], k0, k1, k2);
                    }
                    if (ba0 + R <= NBA - 1) {
                        int b = bt * NBA + ba0 + R;
                        scan_seg(s_off[b], s_off[b + 1], k0, k1, k2);
                    }
                }
            }
            float safe = BIG;
            if (bt0 - R > 0)       safe = fminf(safe, gt - (float)(bt0 - R) * WBIN);
            if (bt0 + R < NBT - 1) safe = fminf(safe, (float)(bt0 + R + 1) * WBIN - gt);
            if (ba0 - R > 0)       safe = fminf(safe, glp - (float)(ba0 - R) * WBIN);
            if (ba0 + R < NBA - 1) safe = fminf(safe, (float)(ba0 + R + 1) * WBIN - glp);
            if (k2 <= safe * safe) done = true;
        }
    }

    // epilogue: indices from keys, exact distances, interp weights
    {
        int i0 = __float_as_uint(k0) & 0x7FF;
        int i1 = __float_as_uint(k1) & 0x7FF;
        int i2 = __float_as_uint(k2) & 0x7FF;
        float2 p0 = s_btl[i0];
        float2 p1 = s_btl[i1];
        float2 p2 = s_btl[i2];
        float dt0 = gt - p0.x, dl0 = gl - p0.y;
        float dt1 = gt - p1.x, dl1 = gl - p1.y;
        float dt2 = gt - p2.x, dl2 = gl - p2.y;
        float d0 = fmaf(dt0, dt0, dl0 * dl0);
        float d1 = fmaf(dt1, dt1, dl1 * dl1);
        float d2 = fmaf(dt2, dt2, dl2 * dl2);
        float s = d0 + d1 + d2;
        row[j] = (d0 * s_br[i0] + d1 * s_br[i1] + d2 * s_br[i2]) / s;
    }
    __syncthreads();

    // DFT: q = wave id (quarter), mm = lane. row reads are wave-uniform
    // (broadcast, conflict-free); ctab gathers per-lane.
    {
        int q = t >> 6;        // 0..3
        int mm = t & 63;       // lane = mode
        if (mm < MMAX) {
            int bs = q * 64;
            float a0 = 0.0f, a1 = 0.0f, a2 = 0.0f, a3 = 0.0f;
            int p = (bs * mm) & (NLON - 1);
            int st1 = mm;
            int st2 = (2 * mm) & (NLON - 1);
            int st3 = (3 * mm) & (NLON - 1);
            int st4 = (4 * mm) & (NLON - 1);
            for (int i = 0; i < 64; i += 4) {
                a0 += row[bs + i] * ctab[p];
                a1 += row[bs + i + 1] * ctab[(p + st1) & (NLON - 1)];
                a2 += row[bs + i + 2] * ctab[(p + st2) & (NLON - 1)];
                a3 += row[bs + i + 3] * ctab[(p + st3) & (NLON - 1)];
                p = (p + st4) & (NLON - 1);
            }
            part[q * 64 + mm] = (a0 + a1) + (a2 + a3);
        }
    }
    __syncthreads();
    if (t < MMAX) {
        float v = ((part[t] + part[64 + t]) + (part[128 + t] + part[192 + t])) *
                  (float)(2.0 * PI_D / (double)NLON);
        fre[(f * NLAT + lat) * MMAX + t] = v;
    }
}

// ---------------------------------------------------------------------------
// Kernel 2: Legendre contraction + loss (R6 verbatim). Block per (b,l);
// 256 threads = (mm 0..63) x (k-quarter 0..3); LDS reduce; one atomic/block.
// ---------------------------------------------------------------------------
__global__ __launch_bounds__(256) void contract_loss(const float* __restrict__ fre,
                                                     const float* __restrict__ pctwT,
                                                     float* __restrict__ out) {
    int b = blockIdx.x / LMAX;
    int l = blockIdx.x % LMAX;
    int mm = threadIdx.x & 63;
    int kq = threadIdx.x >> 6;
    __shared__ float sp[4][64], st_[4][64];
    float pc = 0.0f, tc = 0.0f;
    if (mm < MMAX) {
        const float* pw = pctwT + ((size_t)l * NLAT + kq * 32) * MMAX + mm;
        const float* fp = fre + ((size_t)b * NLAT + kq * 32) * MMAX + mm;
        const float* ft = fre + ((size_t)(2 + b) * NLAT + kq * 32) * MMAX + mm;
#pragma unroll 8
        for (int k = 0; k < 32; ++k) {
            float w = pw[k * MMAX];
            pc += fp[k * MMAX] * w;
            tc += ft[k * MMAX] * w;
        }
    }
    sp[kq][mm] = pc;
    st_[kq][mm] = tc;
    __syncthreads();
    if (threadIdx.x < 64) {
        int m2 = threadIdx.x;
        float pcs = (sp[0][m2] + sp[1][m2]) + (sp[2][m2] + sp[3][m2]);
        float tcs = (st_[0][m2] + st_[1][m2]) + (st_[2][m2] + st_[3][m2]);
        float diff = pcs - tcs;
        double dl_ = (double)(49 - l);
        float rw = (float)exp(-(dl_ * dl_) / 5000.0);
        float contrib = (m2 < MMAX) ? diff * diff * rw * 0.5f : 0.0f;
        for (int off = 32; off > 0; off >>= 1) contrib += __shfl_down(contrib, off);
        if (m2 == 0) atomicAdd(out, contrib);
    }
}

// ---------------------------------------------------------------------------
extern "C" void kernel_launch(void* const* d_in, const int* in_sizes, int n_in,
                              void* d_out, int out_size, void* d_ws, size_t ws_size,
                              hipStream_t stream) {
    const float* pred = (const float*)d_in[0];
    const float* tgt = (const float*)d_in[1];
    float* ws = (float*)d_ws;

    float* pctwT = ws;            // 50*128*50 = 320000 floats
    float* fre   = ws + 320000;   // 4*128*50  =  25600 floats
    float* out = (float*)d_out;

    fused_main<<<640, 256, 0, stream>>>(pred, tgt, pctwT, fre, out);
    contract_loss<<<2 * LMAX, 256, 0, stream>>>(fre, pctwT, out);
}